// Round 4
// baseline (335.558 us; speedup 1.0000x reference)
//
#include <hip/hip_runtime.h>
#include <hip/hip_bf16.h>
#include <math.h>

typedef __bf16 bf16;
typedef unsigned char u8;
typedef unsigned long long ull;
typedef __bf16 bf16x8 __attribute__((ext_vector_type(8)));
typedef float f32x4 __attribute__((ext_vector_type(4)));

#define BB 64
#define NN 256
#define DD 768
#define MM (BB*NN)           // 16384
#define KP 1024              // agg phase-1 K (4 relations * 256)
#define WSZ (DD*DD)          // 589824
#define TL 144               // fp8 transpose buffer row stride (16B-aligned)

// fp8 tiled layout: [tile][koq(4)][m(128)] -> 4096B tiles, koq = (K%32)/8
// g8 tile id: (b*2 + i/128)*32 + K/32          (16 MB total)
// p8 tile id: (b*6 + e/128)*32 + K/32          (50 MB total)

// ---------------- async global->LDS (16B per lane) ----------------
__device__ __forceinline__ void async16(const void* g, void* l) {
  __builtin_amdgcn_global_load_lds((__attribute__((address_space(1))) void*)g,
                                   (__attribute__((address_space(3))) void*)l,
                                   16, 0, 0);
}

// stage a 128x32 bf16 tile (row-major, row stride ld elements) into 8KB LDS
__device__ __forceinline__ void stage_tile(const bf16* gsrc, int ld, char* ldst,
                                           int wv, int lane) {
#pragma unroll
  for (int cc = 0; cc < 2; ++cc) {
    int c = wv * 2 + cc;
    int row = c * 16 + (lane >> 2);
    int col = (lane & 3) * 8;
    async16(gsrc + (size_t)row * ld + col, ldst + c * 1024);
  }
}

// one BK=32 bf16 step (k_agg phase-2 path)
__device__ __forceinline__ void mma_step(const char* lA, const char* lB,
                                         f32x4 acc[4][4], int lane, int wr, int wc) {
  bf16x8 af[4], bfr[4];
  int rbase = wr * 64 + (lane & 15);
  int cbase = wc * 64 + (lane & 15);
  int ko = (lane >> 4) * 8;
#pragma unroll
  for (int r = 0; r < 4; ++r)
    af[r] = *(const bf16x8*)(lA + (((rbase + r * 16) * 32) + ko) * 2);
#pragma unroll
  for (int c = 0; c < 4; ++c)
    bfr[c] = *(const bf16x8*)(lB + (((cbase + c * 16) * 32) + ko) * 2);
#pragma unroll
  for (int r = 0; r < 4; ++r)
#pragma unroll
    for (int c = 0; c < 4; ++c)
      acc[r][c] = __builtin_amdgcn_mfma_f32_16x16x32_bf16(af[r], bfr[c], acc[r][c], 0, 0, 0);
}

// one BK=32 fp8 step on a K-major-8B tiled slab: conflict-free b64 reads
__device__ __forceinline__ void mma_step_fp8t(const char* lA, const char* lB,
                                              f32x4 acc[4][4], int lane, int wr, int wc) {
  long af[4], bfr[4];
  int koq = (lane >> 4) * 1024;
  int mA = (wr * 64 + (lane & 15)) * 8;
  int mB = (wc * 64 + (lane & 15)) * 8;
#pragma unroll
  for (int r = 0; r < 4; ++r)
    af[r] = *(const long*)(lA + koq + mA + r * 128);
#pragma unroll
  for (int c = 0; c < 4; ++c)
    bfr[c] = *(const long*)(lB + koq + mB + c * 128);
#pragma unroll
  for (int r = 0; r < 4; ++r)
#pragma unroll
    for (int c = 0; c < 4; ++c)
      acc[r][c] = __builtin_amdgcn_mfma_f32_16x16x32_fp8_fp8(af[r], bfr[c], acc[r][c], 0, 0, 0);
}

// BK=64 bf16 double-slab K-step (k_agg phase-2 path)
__device__ __forceinline__ void k_step64(const bf16* Ab, int lda, const bf16* Bb, int ldb,
                                         char* smem, f32x4 acc[4][4],
                                         int wv, int lane, int wr, int wc) {
  char* lA0 = smem;
  char* lA1 = smem + 8192;
  char* lB0 = smem + 16384;
  char* lB1 = smem + 24576;
  __syncthreads();
  stage_tile(Ab, lda, lA0, wv, lane);
  stage_tile(Ab + 32, lda, lA1, wv, lane);
  stage_tile(Bb, ldb, lB0, wv, lane);
  stage_tile(Bb + 32, ldb, lB1, wv, lane);
  __builtin_amdgcn_s_waitcnt(0);
  __syncthreads();
  mma_step(lA0, lB0, acc, lane, wr, wc);
  mma_step(lA1, lB1, acc, lane, wr, wc);
}

// pack 4 floats -> 4 fp8(e4m3) in a uint
__device__ __forceinline__ unsigned pack4(float a, float b, float c, float d) {
  int w = 0;
  w = __builtin_amdgcn_cvt_pk_fp8_f32(a, b, w, false);
  w = __builtin_amdgcn_cvt_pk_fp8_f32(c, d, w, true);
  return (unsigned)w;
}

// ---------------- K0: fused prep (dw/cast/zero-neigh) + weight combine ----------------
__global__ void k_pre(const float* __restrict__ node, const float* __restrict__ Wq,
                      const float* __restrict__ bq, bf16* __restrict__ node_bf,
                      float* __restrict__ dw, float* __restrict__ allw,
                      float* __restrict__ neigh,
                      const float* __restrict__ Ws,
                      const float* __restrict__ Wa, const float* __restrict__ Wp,
                      const float* __restrict__ Wap, const float* __restrict__ Wpp,
                      const float* __restrict__ Wa2, const float* __restrict__ Wp2,
                      const float* __restrict__ Wap2, const float* __restrict__ Wpp2,
                      bf16* __restrict__ Wcat4, bf16* __restrict__ Ws_bf) {
  if (blockIdx.x < MM / 4) {
    int lane = threadIdx.x & 63, wv = threadIdx.x >> 6;
    int row = blockIdx.x * 4 + wv;
    const float* nr = node + (size_t)row * DD;
    bf16* nb = node_bf + (size_t)row * DD;
    float s = 0.f;
#pragma unroll
    for (int k = 0; k < DD / 64; ++k) {
      int idx = lane + k * 64;
      float v = nr[idx];
      nb[idx] = (bf16)v;
      s += v * Wq[idx];
    }
#pragma unroll
    for (int off = 32; off; off >>= 1) s += __shfl_down(s, off);
    if (lane == 0) {
      float z = s + bq[0];
      float d = 1.f / (1.f + expf(-z));
      dw[row] = d;
      allw[row] = d;
      neigh[row] = 0.f;
    }
  } else {
    int i = (blockIdx.x - MM / 4) * 256 + threadIdx.x;   // 0..589823
    Ws_bf[i] = (bf16)Ws[i];
    Wcat4[i]           = (bf16)(Wa[i] + Wa2[i]);
    Wcat4[i + WSZ]     = (bf16)(Wp[i] + Wp2[i]);
    Wcat4[i + 2 * WSZ] = (bf16)(Wap[i] + Wap2[i]);
    Wcat4[i + 3 * WSZ] = (bf16)(Wpp[i] + Wpp2[i]);
  }
}

// store a 16B (two 8B koq pieces) value into the tiled fp8 layout
__device__ __forceinline__ void store_tiled(u8* base, int tile, int kin, int m, uint4 v) {
  size_t o = (size_t)tile * 4096 + (size_t)((kin >> 3) * 1024 + m * 8);
  *(ull*)(base + o)        = ((ull)v.y << 32) | v.x;
  *(ull*)(base + o + 1024) = ((ull)v.w << 32) | v.z;
}

// ---------------- K0b: g8 tiled = fp8(dw_src * g_X), neigh (atomic) ----------------
__global__ void k_graph(const int* __restrict__ mask, const int* __restrict__ arg,
                        const int* __restrict__ pun, const float* __restrict__ dw,
                        u8* __restrict__ g8, float* __restrict__ neigh) {
  __shared__ float la[64][65];
  __shared__ float lp[64][65];
  __shared__ float msk[256];
  __shared__ float dwv[256];
  int tid = threadIdx.x;
  int bi = blockIdx.x;
  int b = bi >> 4, it = (bi >> 2) & 3, jt = bi & 3;
  int i0 = it * 64, j0 = jt * 64;
  msk[tid] = (float)mask[b * NN + tid];
  dwv[tid] = dw[b * NN + tid];
  __syncthreads();
  int ir = tid >> 2, c4 = (tid & 3) * 16;
  int i = i0 + ir;
  float mi = msk[i];
  size_t gb = (size_t)b * NN * NN;
  const int* ap = arg + gb + (size_t)i * NN + j0 + c4;
  const int* pp = pun + gb + (size_t)i * NN + j0 + c4;
  float va[16], vp[16];
  float racc = 0.f;
#pragma unroll
  for (int k = 0; k < 16; ++k) {
    int j = j0 + c4 + k;
    float dd = (i == j) ? 0.f : mi * msk[j];
    float ga = dd * (float)ap[k];
    float gp = dd * (float)pp[k];
    la[ir][c4 + k] = ga;
    lp[ir][c4 + k] = gp;
    float w = dwv[j];
    va[k] = w * ga;
    vp[k] = w * gp;
    racc += ga + gp;
  }
  uint4 oa, op;
#pragma unroll
  for (int g = 0; g < 4; ++g) {
    (&oa.x)[g] = pack4(va[g*4], va[g*4+1], va[g*4+2], va[g*4+3]);
    (&op.x)[g] = pack4(vp[g*4], vp[g*4+1], vp[g*4+2], vp[g*4+3]);
  }
  {
    int tR = (b * 2 + (i >> 7)) * 32;
    int K0 = j0 + c4;                       // X=0 K index; X=1 adds 256 (+8 tiles)
    store_tiled(g8, tR + (K0 >> 5),       K0 & 31, i & 127, oa);
    store_tiled(g8, tR + 8 + (K0 >> 5),   K0 & 31, i & 127, op);
  }
  racc += __shfl_xor(racc, 1);
  racc += __shfl_xor(racc, 2);
  if ((tid & 3) == 0) atomicAdd(&neigh[b * NN + i], racc);
  __syncthreads();
  int jr = ir, ic4 = c4;
  float cacc = 0.f;
#pragma unroll
  for (int k = 0; k < 16; ++k) {
    float ga = la[ic4 + k][jr];
    float gp = lp[ic4 + k][jr];
    float w = dwv[i0 + ic4 + k];
    va[k] = w * ga;
    vp[k] = w * gp;
    cacc += ga + gp;
  }
#pragma unroll
  for (int g = 0; g < 4; ++g) {
    (&oa.x)[g] = pack4(va[g*4], va[g*4+1], va[g*4+2], va[g*4+3]);
    (&op.x)[g] = pack4(vp[g*4], vp[g*4+1], vp[g*4+2], vp[g*4+3]);
  }
  {
    int row = j0 + jr;
    int tR = (b * 2 + (row >> 7)) * 32;
    int K2 = i0 + ic4;                      // X=2 base 512 (+16 tiles); X=3 +24
    store_tiled(g8, tR + 16 + (K2 >> 5),  K2 & 31, row & 127, oa);
    store_tiled(g8, tR + 24 + (K2 >> 5),  K2 & 31, row & 127, op);
  }
  cacc += __shfl_xor(cacc, 1);
  cacc += __shfl_xor(cacc, 2);
  if ((tid & 3) == 0) atomicAdd(&neigh[b * NN + j0 + jr], cacc);
}

// ---------------- K1: p8 tiled = fp8((node @ WX^T)^T) ----------------
// v4: 128x128 tile, 4 waves (2Mx2N, wave=64x64), BK=32, THREE 16KB LDS buffers,
// counted vmcnt depth-2, reg-dbuf frags -> ~150-170 regs/wave + 48KB LDS =
// THREE co-resident blocks/CU. Rounds 1-3 showed a single lockstep block
// cannot overlap LDS and MFMA pipes from source (phase = LDS+MFMA summed);
// co-resident independent blocks fill each other's pipe gaps (m114 mechanism).
// Ledger (per wave, 4 loads/tile): prologue stages tiles 0,1,2 -> bufs 0,1,2;
// phase T: vmcnt(4) => tile T+1 resident (own loads) -> s_barrier (=> ALL
// waves' tile T+1 loads done); stage tile T+3 -> buf T%3 (WAR: frags(T) read
// in phase T-1, trailing lgkmcnt(0) + this barrier fence it); ds_read
// frags(T+1) -> alternate reg set; MFMA x16 on current set; trailing
// lgkmcnt(0). Tail: T=22 vmcnt(0); T=23 no wait/reads.
template<int T>
__device__ __forceinline__ void proj_ph(char* smem, int stoff,
                                        const char* gA, const char* gB,
                                        int aoff, int boff,
                                        bf16x8 (&ca)[4], bf16x8 (&cb)[4],
                                        bf16x8 (&na)[4], bf16x8 (&nb)[4],
                                        f32x4 (&acc)[4][4]) {
  if constexpr (T <= 21)      asm volatile("s_waitcnt vmcnt(4)" ::: "memory");
  else if constexpr (T == 22) asm volatile("s_waitcnt vmcnt(0)" ::: "memory");
  __builtin_amdgcn_s_barrier();
  __builtin_amdgcn_sched_barrier(0);
  if constexpr (T + 3 < 24) {                  // stage tile T+3 -> buf T%3
    constexpr int B = (T % 3) * 16384;
    const char* sA = gA + (T + 3) * 64;
    const char* sB = gB + (T + 3) * 64;
    char* D = smem + B + stoff;
    async16(sA,         D);
    async16(sA + 98304, D + 4096);
    async16(sB,         D + 8192);
    async16(sB + 98304, D + 12288);
  }
  if constexpr (T + 1 < 24) {                  // frags(T+1) -> alternate set
    const char* L = smem + ((T + 1) % 3) * 16384;
#pragma unroll
    for (int r = 0; r < 4; ++r) na[r] = *(const bf16x8*)(L + aoff + r * 1024);
#pragma unroll
    for (int c = 0; c < 4; ++c) nb[c] = *(const bf16x8*)(L + boff + c * 1024);
  }
  __builtin_amdgcn_s_setprio(1);
#pragma unroll
  for (int r = 0; r < 4; ++r)
#pragma unroll
    for (int c = 0; c < 4; ++c)
      acc[r][c] = __builtin_amdgcn_mfma_f32_16x16x32_bf16(ca[r], cb[c], acc[r][c], 0, 0, 0);
  __builtin_amdgcn_s_setprio(0);
  asm volatile("s_waitcnt lgkmcnt(0)" ::: "memory");
  __builtin_amdgcn_sched_barrier(0);
}

__global__ __launch_bounds__(256, 3) void k_proj(const bf16* __restrict__ node_bf,
                                                 const bf16* __restrict__ Wcat4,
                                                 u8* __restrict__ p8) {
  __shared__ __align__(16) char smem[49152];
  int tid = threadIdx.x, lane = tid & 63, wv = tid >> 6;
  int wr = wv >> 1, wc = wv & 1;
  // XCD swizzle: the 24 n-tiles of one m-tile share blockIdx%8 (same XCD ->
  // shared 196KB A-panel in that XCD's L2). 3072 % 8 == 0: bijective.
  int l = blockIdx.x, xcd = l & 7, idx = l >> 3;
  int mt = (idx / 24) * 8 + xcd;         // 128 m-tiles of 128 rows
  int nt = idx % 24;                     // 24 n-tiles of 128 over (X,e)
  int m0 = mt * 128;
  int n0 = nt * 128;
  // staging: thread t covers row t>>2 (+64 on round 1), slot t&3, src slot
  // pre-swizzled so linear global_load_lds dest + swizzled ds_read match.
  int srcS = (tid & 3) ^ ((tid >> 3) & 3);
  const char* gA = (const char*)node_bf + (size_t)m0 * 1536 + (tid >> 2) * 1536 + srcS * 16;
  const char* gB = (const char*)Wcat4  + (size_t)n0 * 1536 + (tid >> 2) * 1536 + srcS * 16;
  int stoff = wv * 1024;                 // wave-uniform LDS dest base offset
  // read-side swizzle: slot = (lane>>4) ^ ((row>>1)&3); row%16 = lane&15
  int sSwR = ((lane >> 4) ^ (((lane & 15) >> 1) & 3)) << 4;
  int aoff = (wr * 64 + (lane & 15)) * 64 + sSwR;
  int boff = 8192 + (wc * 64 + (lane & 15)) * 64 + sSwR;
  f32x4 z = {0.f, 0.f, 0.f, 0.f};
  f32x4 acc[4][4];
#pragma unroll
  for (int r = 0; r < 4; ++r)
#pragma unroll
    for (int c = 0; c < 4; ++c) acc[r][c] = z;
  bf16x8 fa0[4], fb0[4], fa1[4], fb1[4];
  // prologue: stage tiles 0,1,2 (12 loads/thread in flight)
#pragma unroll
  for (int u = 0; u < 3; ++u) {
    const char* sA = gA + u * 64;
    const char* sB = gB + u * 64;
    char* D = smem + u * 16384 + stoff;
    async16(sA,         D);
    async16(sA + 98304, D + 4096);
    async16(sB,         D + 8192);
    async16(sB + 98304, D + 12288);
  }
  asm volatile("s_waitcnt vmcnt(8)" ::: "memory");    // tile 0 resident (own)
  __builtin_amdgcn_s_barrier();                       // all waves' tile 0 done
  __builtin_amdgcn_sched_barrier(0);
#pragma unroll
  for (int r = 0; r < 4; ++r) fa0[r] = *(const bf16x8*)(smem + aoff + r * 1024);
#pragma unroll
  for (int c = 0; c < 4; ++c) fb0[c] = *(const bf16x8*)(smem + boff + c * 1024);
  asm volatile("s_waitcnt lgkmcnt(0)" ::: "memory");
  __builtin_amdgcn_sched_barrier(0);
  // main: 24 K-tiles of 32 (K=768), register sets alternate by parity
  proj_ph< 0>(smem, stoff, gA, gB, aoff, boff, fa0, fb0, fa1, fb1, acc);
  proj_ph< 1>(smem, stoff, gA, gB, aoff, boff, fa1, fb1, fa0, fb0, acc);
  proj_ph< 2>(smem, stoff, gA, gB, aoff, boff, fa0, fb0, fa1, fb1, acc);
  proj_ph< 3>(smem, stoff, gA, gB, aoff, boff, fa1, fb1, fa0, fb0, acc);
  proj_ph< 4>(smem, stoff, gA, gB, aoff, boff, fa0, fb0, fa1, fb1, acc);
  proj_ph< 5>(smem, stoff, gA, gB, aoff, boff, fa1, fb1, fa0, fb0, acc);
  proj_ph< 6>(smem, stoff, gA, gB, aoff, boff, fa0, fb0, fa1, fb1, acc);
  proj_ph< 7>(smem, stoff, gA, gB, aoff, boff, fa1, fb1, fa0, fb0, acc);
  proj_ph< 8>(smem, stoff, gA, gB, aoff, boff, fa0, fb0, fa1, fb1, acc);
  proj_ph< 9>(smem, stoff, gA, gB, aoff, boff, fa1, fb1, fa0, fb0, acc);
  proj_ph<10>(smem, stoff, gA, gB, aoff, boff, fa0, fb0, fa1, fb1, acc);
  proj_ph<11>(smem, stoff, gA, gB, aoff, boff, fa1, fb1, fa0, fb0, acc);
  proj_ph<12>(smem, stoff, gA, gB, aoff, boff, fa0, fb0, fa1, fb1, acc);
  proj_ph<13>(smem, stoff, gA, gB, aoff, boff, fa1, fb1, fa0, fb0, acc);
  proj_ph<14>(smem, stoff, gA, gB, aoff, boff, fa0, fb0, fa1, fb1, acc);
  proj_ph<15>(smem, stoff, gA, gB, aoff, boff, fa1, fb1, fa0, fb0, acc);
  proj_ph<16>(smem, stoff, gA, gB, aoff, boff, fa0, fb0, fa1, fb1, acc);
  proj_ph<17>(smem, stoff, gA, gB, aoff, boff, fa1, fb1, fa0, fb0, acc);
  proj_ph<18>(smem, stoff, gA, gB, aoff, boff, fa0, fb0, fa1, fb1, acc);
  proj_ph<19>(smem, stoff, gA, gB, aoff, boff, fa1, fb1, fa0, fb0, acc);
  proj_ph<20>(smem, stoff, gA, gB, aoff, boff, fa0, fb0, fa1, fb1, acc);
  proj_ph<21>(smem, stoff, gA, gB, aoff, boff, fa1, fb1, fa0, fb0, acc);
  proj_ph<22>(smem, stoff, gA, gB, aoff, boff, fa0, fb0, fa1, fb1, acc);
  proj_ph<23>(smem, stoff, gA, gB, aoff, boff, fa1, fb1, fa0, fb0, acc);
  // epilogue: C^T -> fp8 -> tiled p8 (round-0-verified 128x128 path)
  __syncthreads();
  u8* tb = (u8*)smem;                    // [128 n][TL] fp8
  int b = m0 >> 8, j0 = m0 & 255;
  int X = nt / 6, e0 = (nt % 6) * 128;
#pragma unroll
  for (int r = 0; r < 4; ++r)
#pragma unroll
    for (int c = 0; c < 4; ++c) {
      int n = wc * 64 + c * 16 + (lane & 15);
      int m = wr * 64 + r * 16 + ((lane >> 4) << 2);
      *(unsigned*)(tb + n * TL + m) =
          pack4(acc[r][c][0], acc[r][c][1], acc[r][c][2], acc[r][c][3]);
    }
  __syncthreads();
  int tR = (b * 6 + (e0 >> 7)) * 32 + X * 8;
#pragma unroll
  for (int t2 = 0; t2 < 4; ++t2) {
    int row = t2 * 32 + (tid >> 3);      // e offset 0..127
    int col = (tid & 7) * 16;            // j offset
    uint4 v = *(const uint4*)(tb + row * TL + col);
    int K = j0 + col;
    store_tiled(p8, tR + (K >> 5), K & 31, row, v);
  }
}

// ---------------- K2: out = relu(rdenom*(g8 @ p8) + node @ Ws^T + bs) ----------------
// XCD swizzle: all 12 blocks of one b share blockIdx%8 (-> same XCD under RR dispatch).
__global__ __launch_bounds__(256) void k_agg(const u8* __restrict__ g8,
                                             const u8* __restrict__ p8,
                                             const bf16* __restrict__ node_bf,
                                             const bf16* __restrict__ Ws_bf,
                                             const float* __restrict__ neigh,
                                             const float* __restrict__ bs,
                                             float* __restrict__ out) {
  __shared__ __align__(16) char smem[32768];
  int tid = threadIdx.x, lane = tid & 63, wv = tid >> 6, wr = wv >> 1, wc = wv & 1;
  int l = blockIdx.x;
  int xcd = l & 7, idx = l >> 3;
  int b = (idx / 12) * 8 + xcd;
  int t = idx % 12;
  int i0 = (t / 6) * 128, e0 = (t % 6) * 128;
  f32x4 z = {0.f, 0.f, 0.f, 0.f};
  f32x4 acc[4][4];
#pragma unroll
  for (int r = 0; r < 4; ++r)
#pragma unroll
    for (int c = 0; c < 4; ++c) acc[r][c] = z;
  // phase 1: agg_raw = g8 @ p8_b (K = 1024, fp8 tiled, BK=128, conflict-free)
  const u8* At = g8 + (size_t)((b * 2 + (i0 >> 7)) * 32) * 4096;
  const u8* Bt = p8 + (size_t)((b * 6 + (e0 >> 7)) * 32) * 4096;
  int lsoff = wv * 1024;
  int goff = lsoff + lane * 16;
  for (int k0 = 0; k0 < KP; k0 += 128) {
    __syncthreads();
#pragma unroll
    for (int s = 0; s < 4; ++s) {
      size_t toff = (size_t)((k0 >> 5) + s) * 4096 + goff;
      async16(At + toff, smem + s * 4096 + lsoff);
      async16(Bt + toff, smem + 16384 + s * 4096 + lsoff);
    }
    __builtin_amdgcn_s_waitcnt(0);
    __syncthreads();
#pragma unroll
    for (int s = 0; s < 4; ++s)
      mma_step_fp8t(smem + s * 4096, smem + 16384 + s * 4096, acc, lane, wr, wc);
  }
  // inter-phase: scale by 1/denom
  int rowb = i0 + wr * 64 + (lane >> 4) * 4;
#pragma unroll
  for (int r = 0; r < 4; ++r)
#pragma unroll
    for (int q = 0; q < 4; ++q) {
      float rd = 1.f / fmaxf(neigh[b * NN + rowb + r * 16 + q], 1.f);
#pragma unroll
      for (int c = 0; c < 4; ++c) acc[r][c][q] *= rd;
    }
  // phase 2: + node @ Ws^T (K = 768, bf16 — fp8 here would blow the absmax tail)
  const bf16* Ab2 = node_bf + (size_t)(b * NN + i0) * DD;
  const bf16* Bb2 = Ws_bf + (size_t)e0 * DD;
  for (int k0 = 0; k0 < DD; k0 += 64)
    k_step64(Ab2 + k0, DD, Bb2 + k0, DD, smem, acc, wv, lane, wr, wc);
  // epilogue: relu(acc + bs) -> out (written exactly once)
  int colb = e0 + wc * 64 + (lane & 15);
#pragma unroll
  for (int c = 0; c < 4; ++c) {
    int col = colb + c * 16;
    float bv = bs[col];
#pragma unroll
    for (int r = 0; r < 4; ++r)
#pragma unroll
      for (int q = 0; q < 4; ++q) {
        int m = b * NN + rowb + r * 16 + q;
        out[(size_t)m * DD + col] = fmaxf(acc[r][c][q] + bv, 0.f);
      }
  }
}

// ---------------- launch ----------------
extern "C" void kernel_launch(void* const* d_in, const int* in_sizes, int n_in,
                              void* d_out, int out_size, void* d_ws, size_t ws_size,
                              hipStream_t stream) {
  const float* node = (const float*)d_in[0];
  const int* mask   = (const int*)d_in[1];
  const int* arg    = (const int*)d_in[2];
  const int* pun    = (const int*)d_in[3];
  const float* Wq   = (const float*)d_in[4];
  const float* bq   = (const float*)d_in[5];
  const float* Ws   = (const float*)d_in[6];
  const float* bs   = (const float*)d_in[7];
  const float* Wa   = (const float*)d_in[8];
  const float* Wp   = (const float*)d_in[9];
  const float* Wap  = (const float*)d_in[10];
  const float* Wpp  = (const float*)d_in[11];
  const float* Wa2  = (const float*)d_in[12];
  const float* Wp2  = (const float*)d_in[13];
  const float* Wap2 = (const float*)d_in[14];
  const float* Wpp2 = (const float*)d_in[15];

  float* out  = (float*)d_out;              // node: 16384*768 fp32
  float* allw = out + (size_t)MM * DD;      // all_weight: 16384 fp32

  char* ws = (char*)d_ws;
  bf16* node_bf = (bf16*)ws;                    // 25,165,824 B
  float* dw     = (float*)(ws + 25165824);      //     65,536 B
  float* neigh  = (float*)(ws + 25231360);      //     65,536 B
  bf16* Wcat4   = (bf16*)(ws + 25296896);       //  4,718,592 B  bf16 combined rel weights
  bf16* Ws_bf   = (bf16*)(ws + 30015488);       //  1,179,648 B
  u8*   g8      = (u8*)(ws + 31195136);         // 16,777,216 B  fp8 tiled
  u8*   p8      = (u8*)(ws + 47972352);         // 50,331,648 B  fp8 tiled
  (void)ws_size; (void)in_sizes; (void)n_in; (void)out_size;

  k_pre<<<MM / 4 + WSZ / 256, 256, 0, stream>>>(node, Wq, bq, node_bf, dw, allw,
                                                neigh, Ws, Wa, Wp, Wap, Wpp,
                                                Wa2, Wp2, Wap2, Wpp2, Wcat4, Ws_bf);
  k_graph<<<BB * 16, 256, 0, stream>>>(mask, arg, pun, dw, g8, neigh);
  k_proj<<<3072, 256, 0, stream>>>(node_bf, Wcat4, p8);
  k_agg<<<12 * BB, 256, 0, stream>>>(g8, p8, node_bf, Ws_bf, neigh, bs, out);
}

// Round 5
// 307.651 us; speedup vs baseline: 1.0907x; 1.0907x over previous
//
#include <hip/hip_runtime.h>
#include <hip/hip_bf16.h>
#include <math.h>

typedef __bf16 bf16;
typedef unsigned char u8;
typedef unsigned long long ull;
typedef __bf16 bf16x8 __attribute__((ext_vector_type(8)));
typedef float f32x4 __attribute__((ext_vector_type(4)));

#define BB 64
#define NN 256
#define DD 768
#define MM (BB*NN)           // 16384
#define KP 1024              // agg phase-1 K (4 relations * 256)
#define WSZ (DD*DD)          // 589824
#define TL2 272              // fp8 transpose buffer row stride (16B-aligned)
#define AROW2 196608         // 128 rows * 1536 B (staging round-1 offset)

// fp8 tiled layout: [tile][koq(4)][m(128)] -> 4096B tiles, koq = (K%32)/8
// g8 tile id: (b*2 + i/128)*32 + K/32          (16 MB total)
// p8 tile id: (b*6 + e/128)*32 + K/32          (50 MB total)

// ---------------- async global->LDS (16B per lane) ----------------
__device__ __forceinline__ void async16(const void* g, void* l) {
  __builtin_amdgcn_global_load_lds((__attribute__((address_space(1))) void*)g,
                                   (__attribute__((address_space(3))) void*)l,
                                   16, 0, 0);
}

// one BK=32 fp8 step on a K-major-8B tiled slab: conflict-free b64 reads
__device__ __forceinline__ void mma_step_fp8t(const char* lA, const char* lB,
                                              f32x4 acc[4][4], int lane, int wr, int wc) {
  long af[4], bfr[4];
  int koq = (lane >> 4) * 1024;
  int mA = (wr * 64 + (lane & 15)) * 8;
  int mB = (wc * 64 + (lane & 15)) * 8;
#pragma unroll
  for (int r = 0; r < 4; ++r)
    af[r] = *(const long*)(lA + koq + mA + r * 128);
#pragma unroll
  for (int c = 0; c < 4; ++c)
    bfr[c] = *(const long*)(lB + koq + mB + c * 128);
#pragma unroll
  for (int r = 0; r < 4; ++r)
#pragma unroll
    for (int c = 0; c < 4; ++c)
      acc[r][c] = __builtin_amdgcn_mfma_f32_16x16x32_fp8_fp8(af[r], bfr[c], acc[r][c], 0, 0, 0);
}

// one BK=32 bf16 step on a swizzled [128][32] slab (row 64B; slot ^= (row>>1)&3)
__device__ __forceinline__ void mma_step_sw(const char* lA, const char* lB,
                                            f32x4 acc[4][4], int lane, int wr, int wc) {
  bf16x8 af[4], bfr[4];
  int rbase = wr * 64 + (lane & 15);
  int cbase = wc * 64 + (lane & 15);
  int sSw = ((lane >> 4) ^ (((lane & 15) >> 1) & 3)) * 16;
#pragma unroll
  for (int r = 0; r < 4; ++r)
    af[r] = *(const bf16x8*)(lA + (rbase + r * 16) * 64 + sSw);
#pragma unroll
  for (int c = 0; c < 4; ++c)
    bfr[c] = *(const bf16x8*)(lB + (cbase + c * 16) * 64 + sSw);
#pragma unroll
  for (int r = 0; r < 4; ++r)
#pragma unroll
    for (int c = 0; c < 4; ++c)
      acc[r][c] = __builtin_amdgcn_mfma_f32_16x16x32_bf16(af[r], bfr[c], acc[r][c], 0, 0, 0);
}

// pack 4 floats -> 4 fp8(e4m3) in a uint
__device__ __forceinline__ unsigned pack4(float a, float b, float c, float d) {
  int w = 0;
  w = __builtin_amdgcn_cvt_pk_fp8_f32(a, b, w, false);
  w = __builtin_amdgcn_cvt_pk_fp8_f32(c, d, w, true);
  return (unsigned)w;
}

// ---------------- K0: fused prep (dw/cast/zero-neigh) + weight combine ----------------
__global__ void k_pre(const float* __restrict__ node, const float* __restrict__ Wq,
                      const float* __restrict__ bq, bf16* __restrict__ node_bf,
                      float* __restrict__ dw, float* __restrict__ allw,
                      float* __restrict__ neigh,
                      const float* __restrict__ Ws,
                      const float* __restrict__ Wa, const float* __restrict__ Wp,
                      const float* __restrict__ Wap, const float* __restrict__ Wpp,
                      const float* __restrict__ Wa2, const float* __restrict__ Wp2,
                      const float* __restrict__ Wap2, const float* __restrict__ Wpp2,
                      bf16* __restrict__ Wcat4, bf16* __restrict__ Ws_bf) {
  if (blockIdx.x < MM / 4) {
    int lane = threadIdx.x & 63, wv = threadIdx.x >> 6;
    int row = blockIdx.x * 4 + wv;
    const float* nr = node + (size_t)row * DD;
    bf16* nb = node_bf + (size_t)row * DD;
    float s = 0.f;
#pragma unroll
    for (int k = 0; k < DD / 64; ++k) {
      int idx = lane + k * 64;
      float v = nr[idx];
      nb[idx] = (bf16)v;
      s += v * Wq[idx];
    }
#pragma unroll
    for (int off = 32; off; off >>= 1) s += __shfl_down(s, off);
    if (lane == 0) {
      float z = s + bq[0];
      float d = 1.f / (1.f + expf(-z));
      dw[row] = d;
      allw[row] = d;
      neigh[row] = 0.f;
    }
  } else {
    int i = (blockIdx.x - MM / 4) * 256 + threadIdx.x;   // 0..589823
    Ws_bf[i] = (bf16)Ws[i];
    Wcat4[i]           = (bf16)(Wa[i] + Wa2[i]);
    Wcat4[i + WSZ]     = (bf16)(Wp[i] + Wp2[i]);
    Wcat4[i + 2 * WSZ] = (bf16)(Wap[i] + Wap2[i]);
    Wcat4[i + 3 * WSZ] = (bf16)(Wpp[i] + Wpp2[i]);
  }
}

// store a 16B (two 8B koq pieces) value into the tiled fp8 layout
__device__ __forceinline__ void store_tiled(u8* base, int tile, int kin, int m, uint4 v) {
  size_t o = (size_t)tile * 4096 + (size_t)((kin >> 3) * 1024 + m * 8);
  *(ull*)(base + o)        = ((ull)v.y << 32) | v.x;
  *(ull*)(base + o + 1024) = ((ull)v.w << 32) | v.z;
}

// ---------------- K0b: g8 tiled = fp8(dw_src * g_X), neigh (atomic) ----------------
__global__ void k_graph(const int* __restrict__ mask, const int* __restrict__ arg,
                        const int* __restrict__ pun, const float* __restrict__ dw,
                        u8* __restrict__ g8, float* __restrict__ neigh) {
  __shared__ float la[64][65];
  __shared__ float lp[64][65];
  __shared__ float msk[256];
  __shared__ float dwv[256];
  int tid = threadIdx.x;
  int bi = blockIdx.x;
  int b = bi >> 4, it = (bi >> 2) & 3, jt = bi & 3;
  int i0 = it * 64, j0 = jt * 64;
  msk[tid] = (float)mask[b * NN + tid];
  dwv[tid] = dw[b * NN + tid];
  __syncthreads();
  int ir = tid >> 2, c4 = (tid & 3) * 16;
  int i = i0 + ir;
  float mi = msk[i];
  size_t gb = (size_t)b * NN * NN;
  const int* ap = arg + gb + (size_t)i * NN + j0 + c4;
  const int* pp = pun + gb + (size_t)i * NN + j0 + c4;
  float va[16], vp[16];
  float racc = 0.f;
#pragma unroll
  for (int k = 0; k < 16; ++k) {
    int j = j0 + c4 + k;
    float dd = (i == j) ? 0.f : mi * msk[j];
    float ga = dd * (float)ap[k];
    float gp = dd * (float)pp[k];
    la[ir][c4 + k] = ga;
    lp[ir][c4 + k] = gp;
    float w = dwv[j];
    va[k] = w * ga;
    vp[k] = w * gp;
    racc += ga + gp;
  }
  uint4 oa, op;
#pragma unroll
  for (int g = 0; g < 4; ++g) {
    (&oa.x)[g] = pack4(va[g*4], va[g*4+1], va[g*4+2], va[g*4+3]);
    (&op.x)[g] = pack4(vp[g*4], vp[g*4+1], vp[g*4+2], vp[g*4+3]);
  }
  {
    int tR = (b * 2 + (i >> 7)) * 32;
    int K0 = j0 + c4;                       // X=0 K index; X=1 adds 256 (+8 tiles)
    store_tiled(g8, tR + (K0 >> 5),       K0 & 31, i & 127, oa);
    store_tiled(g8, tR + 8 + (K0 >> 5),   K0 & 31, i & 127, op);
  }
  racc += __shfl_xor(racc, 1);
  racc += __shfl_xor(racc, 2);
  if ((tid & 3) == 0) atomicAdd(&neigh[b * NN + i], racc);
  __syncthreads();
  int jr = ir, ic4 = c4;
  float cacc = 0.f;
#pragma unroll
  for (int k = 0; k < 16; ++k) {
    float ga = la[ic4 + k][jr];
    float gp = lp[ic4 + k][jr];
    float w = dwv[i0 + ic4 + k];
    va[k] = w * ga;
    vp[k] = w * gp;
    cacc += ga + gp;
  }
#pragma unroll
  for (int g = 0; g < 4; ++g) {
    (&oa.x)[g] = pack4(va[g*4], va[g*4+1], va[g*4+2], va[g*4+3]);
    (&op.x)[g] = pack4(vp[g*4], vp[g*4+1], vp[g*4+2], vp[g*4+3]);
  }
  {
    int row = j0 + jr;
    int tR = (b * 2 + (row >> 7)) * 32;
    int K2 = i0 + ic4;                      // X=2 base 512 (+16 tiles); X=3 +24
    store_tiled(g8, tR + 16 + (K2 >> 5),  K2 & 31, row & 127, oa);
    store_tiled(g8, tR + 24 + (K2 >> 5),  K2 & 31, row & 127, op);
  }
  cacc += __shfl_xor(cacc, 1);
  cacc += __shfl_xor(cacc, 2);
  if ((tid & 3) == 0) atomicAdd(&neigh[b * NN + j0 + jr], cacc);
}

// ---------------- K1: p8 tiled = fp8((node @ WX^T)^T) ----------------
// Round-2 version (best measured: 81.0 us). 256x256 tile, 8 waves, BK=32,
// 4 LDS buffers, reg-dbuf frags, one barrier/phase, counted vmcnt(8).
template<int T>
__device__ __forceinline__ void proj_ph(char* smem, int wvoff,
                                        const char* gA, const char* gB,
                                        int aoff, int boff,
                                        bf16x8 (&ca)[8], bf16x8 (&cb)[4],
                                        bf16x8 (&na)[8], bf16x8 (&nb)[4],
                                        f32x4 (&acc)[8][4]) {
  if constexpr (T <= 20)      asm volatile("s_waitcnt vmcnt(8)" ::: "memory");
  else if constexpr (T == 21) asm volatile("s_waitcnt vmcnt(4)" ::: "memory");
  else                        asm volatile("s_waitcnt vmcnt(0)" ::: "memory");
  __builtin_amdgcn_s_barrier();
  __builtin_amdgcn_sched_barrier(0);
  if constexpr (T + 4 < 24) {                 // stage tile T+4 -> buf T&3
    char* D = smem + (T & 3) * 32768 + wvoff;
    const char* sA = gA + (T + 4) * 64;
    const char* sB = gB + (T + 4) * 64;
    async16(sA,         D);
    async16(sA + AROW2, D + 8192);
    async16(sB,         D + 16384);
    async16(sB + AROW2, D + 24576);
  }
  if constexpr (T + 1 < 24) {                 // frags(T+1) -> alternate set
    const char* L = smem + ((T + 1) & 3) * 32768;
#pragma unroll
    for (int r = 0; r < 8; ++r) na[r] = *(const bf16x8*)(L + aoff + r * 1024);
#pragma unroll
    for (int c = 0; c < 4; ++c) nb[c] = *(const bf16x8*)(L + boff + c * 1024);
  }
  __builtin_amdgcn_s_setprio(1);
#pragma unroll
  for (int r = 0; r < 8; ++r)
#pragma unroll
    for (int c = 0; c < 4; ++c)
      acc[r][c] = __builtin_amdgcn_mfma_f32_16x16x32_bf16(ca[r], cb[c], acc[r][c], 0, 0, 0);
  __builtin_amdgcn_s_setprio(0);
  asm volatile("s_waitcnt lgkmcnt(0)" ::: "memory");
  __builtin_amdgcn_sched_barrier(0);
}

__global__ __launch_bounds__(512, 2) void k_proj(const bf16* __restrict__ node_bf,
                                                 const bf16* __restrict__ Wcat4,
                                                 u8* __restrict__ p8) {
  __shared__ __align__(16) char smem[131072];
  int tid = threadIdx.x, lane = tid & 63, wv = tid >> 6;
  int wr = wv >> 2, wc = wv & 3;
  int l = blockIdx.x, xcd = l & 7, idx = l >> 3;
  int b = (idx / 12) * 8 + xcd;          // 64 b-tiles (M-tile = one full b)
  int nt = idx % 12;                     // 12 N-tiles of 256 over (X,e)
  int n0 = nt * 256;
  int m0 = b * 256;
  int srcS = (tid & 3) ^ ((tid >> 3) & 3);
  const char* gA = (const char*)node_bf + (size_t)m0 * 1536 + (tid >> 2) * 1536 + srcS * 16;
  const char* gB = (const char*)Wcat4  + (size_t)n0 * 1536 + (tid >> 2) * 1536 + srcS * 16;
  int wvoff = wv * 1024;
  int sSwR = ((lane >> 4) ^ (((lane & 15) >> 1) & 3)) << 4;
  int aoff = (wr * 128 + (lane & 15)) * 64 + sSwR;
  int boff = 16384 + (wc * 64 + (lane & 15)) * 64 + sSwR;
  f32x4 z = {0.f, 0.f, 0.f, 0.f};
  f32x4 acc[8][4];
#pragma unroll
  for (int r = 0; r < 8; ++r)
#pragma unroll
    for (int c = 0; c < 4; ++c) acc[r][c] = z;
  bf16x8 fa0[8], fb0[4], fa1[8], fb1[4];
#pragma unroll
  for (int u = 0; u < 4; ++u) {
    char* D = smem + u * 32768 + wvoff;
    const char* sA = gA + u * 64;
    const char* sB = gB + u * 64;
    async16(sA,         D);
    async16(sA + AROW2, D + 8192);
    async16(sB,         D + 16384);
    async16(sB + AROW2, D + 24576);
  }
  asm volatile("s_waitcnt vmcnt(12)" ::: "memory");   // tile 0 resident
  __builtin_amdgcn_s_barrier();
  __builtin_amdgcn_sched_barrier(0);
#pragma unroll
  for (int r = 0; r < 8; ++r) fa0[r] = *(const bf16x8*)(smem + aoff + r * 1024);
#pragma unroll
  for (int c = 0; c < 4; ++c) fb0[c] = *(const bf16x8*)(smem + boff + c * 1024);
  asm volatile("s_waitcnt lgkmcnt(0)" ::: "memory");
  __builtin_amdgcn_sched_barrier(0);
  proj_ph< 0>(smem, wvoff, gA, gB, aoff, boff, fa0, fb0, fa1, fb1, acc);
  proj_ph< 1>(smem, wvoff, gA, gB, aoff, boff, fa1, fb1, fa0, fb0, acc);
  proj_ph< 2>(smem, wvoff, gA, gB, aoff, boff, fa0, fb0, fa1, fb1, acc);
  proj_ph< 3>(smem, wvoff, gA, gB, aoff, boff, fa1, fb1, fa0, fb0, acc);
  proj_ph< 4>(smem, wvoff, gA, gB, aoff, boff, fa0, fb0, fa1, fb1, acc);
  proj_ph< 5>(smem, wvoff, gA, gB, aoff, boff, fa1, fb1, fa0, fb0, acc);
  proj_ph< 6>(smem, wvoff, gA, gB, aoff, boff, fa0, fb0, fa1, fb1, acc);
  proj_ph< 7>(smem, wvoff, gA, gB, aoff, boff, fa1, fb1, fa0, fb0, acc);
  proj_ph< 8>(smem, wvoff, gA, gB, aoff, boff, fa0, fb0, fa1, fb1, acc);
  proj_ph< 9>(smem, wvoff, gA, gB, aoff, boff, fa1, fb1, fa0, fb0, acc);
  proj_ph<10>(smem, wvoff, gA, gB, aoff, boff, fa0, fb0, fa1, fb1, acc);
  proj_ph<11>(smem, wvoff, gA, gB, aoff, boff, fa1, fb1, fa0, fb0, acc);
  proj_ph<12>(smem, wvoff, gA, gB, aoff, boff, fa0, fb0, fa1, fb1, acc);
  proj_ph<13>(smem, wvoff, gA, gB, aoff, boff, fa1, fb1, fa0, fb0, acc);
  proj_ph<14>(smem, wvoff, gA, gB, aoff, boff, fa0, fb0, fa1, fb1, acc);
  proj_ph<15>(smem, wvoff, gA, gB, aoff, boff, fa1, fb1, fa0, fb0, acc);
  proj_ph<16>(smem, wvoff, gA, gB, aoff, boff, fa0, fb0, fa1, fb1, acc);
  proj_ph<17>(smem, wvoff, gA, gB, aoff, boff, fa1, fb1, fa0, fb0, acc);
  proj_ph<18>(smem, wvoff, gA, gB, aoff, boff, fa0, fb0, fa1, fb1, acc);
  proj_ph<19>(smem, wvoff, gA, gB, aoff, boff, fa1, fb1, fa0, fb0, acc);
  proj_ph<20>(smem, wvoff, gA, gB, aoff, boff, fa0, fb0, fa1, fb1, acc);
  proj_ph<21>(smem, wvoff, gA, gB, aoff, boff, fa1, fb1, fa0, fb0, acc);
  proj_ph<22>(smem, wvoff, gA, gB, aoff, boff, fa0, fb0, fa1, fb1, acc);
  proj_ph<23>(smem, wvoff, gA, gB, aoff, boff, fa1, fb1, fa0, fb0, acc);
  // epilogue: C^T -> fp8 -> tiled p8
  __syncthreads();
  u8* tb = (u8*)smem;                    // [256 n][TL2] fp8
  int X = n0 / DD, e0 = n0 % DD;
#pragma unroll
  for (int r = 0; r < 8; ++r)
#pragma unroll
    for (int c = 0; c < 4; ++c) {
      int n = wc * 64 + c * 16 + (lane & 15);
      int m = wr * 128 + r * 16 + ((lane >> 4) << 2);
      *(unsigned*)(tb + n * TL2 + m) =
          pack4(acc[r][c][0], acc[r][c][1], acc[r][c][2], acc[r][c][3]);
    }
  __syncthreads();
#pragma unroll
  for (int t2 = 0; t2 < 8; ++t2) {
    int erow = t2 * 32 + (tid & 31);     // e offset 0..255
    int col = (tid >> 5) * 16;           // j offset 0..240
    uint4 v = *(const uint4*)(tb + erow * TL2 + col);
    int e = e0 + erow;
    int tR = (b * 6 + (e >> 7)) * 32 + X * 8;
    store_tiled(p8, tR + (col >> 5), col & 31, e & 127, v);
  }
}

// ---------------- K2: out = relu(rdenom*(g8 @ p8) + node @ Ws^T + bs) ----------------
// v2: both K-loops as counted-vmcnt depth-2 pipelines over 3x16KB LDS bufs
// (48KB + small regs -> 3 blocks/CU, grid 768 = exactly 3/CU: cross-block
// m114 overlap replaces the old waitcnt(0)+double-barrier full drains).
// Ledger per phase s: vmcnt(4) => step s resident (own 4 loads); s_barrier
// (all waves); stage step s+2 -> buf (s+2)%3 (= buf of step s-1, whose reads
// drained via MFMA dependency before this barrier); MFMA on buf s%3.
// Tail vmcnt 4 -> 0. Phase 2 uses the proven both-sides XOR swizzle
// (src col slot ^ (lane>>3)&3 staged linear; read slot ^ ((lane&15)>>1)&3)
// -> 2-way (free) instead of 8-way bank conflict on the 64B-row tiles.
__global__ __launch_bounds__(256, 3) void k_agg(const u8* __restrict__ g8,
                                                const u8* __restrict__ p8,
                                                const bf16* __restrict__ node_bf,
                                                const bf16* __restrict__ Ws_bf,
                                                const float* __restrict__ neigh,
                                                const float* __restrict__ bs,
                                                float* __restrict__ out) {
  __shared__ __align__(16) char smem[49152];
  int tid = threadIdx.x, lane = tid & 63, wv = tid >> 6, wr = wv >> 1, wc = wv & 1;
  int l = blockIdx.x;
  int xcd = l & 7, idx = l >> 3;
  int b = (idx / 12) * 8 + xcd;
  int t = idx % 12;
  int i0 = (t / 6) * 128, e0 = (t % 6) * 128;
  f32x4 z = {0.f, 0.f, 0.f, 0.f};
  f32x4 acc[4][4];
#pragma unroll
  for (int r = 0; r < 4; ++r)
#pragma unroll
    for (int c = 0; c < 4; ++c) acc[r][c] = z;
  // ---- phase 1: agg_raw = g8 @ p8 (K=1024 fp8 tiled, BK=64/step, 16 steps) ----
  const u8* At = g8 + (size_t)((b * 2 + (i0 >> 7)) * 32) * 4096;
  const u8* Bt = p8 + (size_t)((b * 6 + (e0 >> 7)) * 32) * 4096;
  int gOff = tid * 16;                   // linear 16B slot within a 4KB tile
  int lOff = wv * 1024;                  // wave-uniform LDS dest base
  // prologue: stage steps 0,1 -> bufs 0,1 (8 loads/thread in flight)
#pragma unroll
  for (int u = 0; u < 2; ++u) {
    char* D = smem + u * 16384 + lOff;
    const u8* a0 = At + (size_t)(2 * u) * 4096 + gOff;
    const u8* b0 = Bt + (size_t)(2 * u) * 4096 + gOff;
    async16(a0, D);            async16(a0 + 4096, D + 4096);
    async16(b0, D + 8192);     async16(b0 + 4096, D + 12288);
  }
  for (int s = 0; s < 16; ++s) {
    if (s <= 14) asm volatile("s_waitcnt vmcnt(4)" ::: "memory");
    else         asm volatile("s_waitcnt vmcnt(0)" ::: "memory");
    __builtin_amdgcn_s_barrier();
    if (s + 2 < 16) {                    // stage step s+2 -> buf (s+2)%3
      char* D = smem + ((s + 2) % 3) * 16384 + lOff;
      const u8* a0 = At + (size_t)(2 * (s + 2)) * 4096 + gOff;
      const u8* b0 = Bt + (size_t)(2 * (s + 2)) * 4096 + gOff;
      async16(a0, D);          async16(a0 + 4096, D + 4096);
      async16(b0, D + 8192);   async16(b0 + 4096, D + 12288);
    }
    const char* L = smem + (s % 3) * 16384;
    __builtin_amdgcn_s_setprio(1);
    mma_step_fp8t(L,        L + 8192,  acc, lane, wr, wc);
    mma_step_fp8t(L + 4096, L + 12288, acc, lane, wr, wc);
    __builtin_amdgcn_s_setprio(0);
  }
  // inter-phase: scale by 1/denom (registers only)
  int rowb = i0 + wr * 64 + (lane >> 4) * 4;
#pragma unroll
  for (int r = 0; r < 4; ++r)
#pragma unroll
    for (int q = 0; q < 4; ++q) {
      float rd = 1.f / fmaxf(neigh[b * NN + rowb + r * 16 + q], 1.f);
#pragma unroll
      for (int c = 0; c < 4; ++c) acc[r][c][q] *= rd;
    }
  __syncthreads();                       // all phase-1 reads done before reuse
  // ---- phase 2: + node @ Ws^T (K=768 bf16, BK=32/step, 24 steps) ----
  const bf16* Ab2 = node_bf + (size_t)(b * NN + i0) * DD;
  const bf16* Bb2 = Ws_bf + (size_t)e0 * DD;
  int srow = (tid >> 2);                 // 0..63: rows (c*16 + lane>>2) via c
  int scol = ((lane & 3) ^ ((lane >> 3) & 3)) * 8;   // pre-swizzled src col
  // stage step u (k0 = u*32) -> buf u%3: A tile @0, B tile @8192
#define STAGE2(u)                                                              \
  {                                                                            \
    char* D = smem + ((u) % 3) * 16384;                                        \
    _Pragma("unroll")                                                          \
    for (int cc = 0; cc < 2; ++cc) {                                           \
      int c = wv * 2 + cc;                                                     \
      int row = c * 16 + (lane >> 2);                                          \
      async16(Ab2 + (size_t)row * DD + (u) * 32 + scol, D + c * 1024);         \
      async16(Bb2 + (size_t)row * DD + (u) * 32 + scol, D + 8192 + c * 1024);  \
    }                                                                          \
  }
  STAGE2(0);
  STAGE2(1);
  for (int s = 0; s < 24; ++s) {
    if (s <= 22) asm volatile("s_waitcnt vmcnt(4)" ::: "memory");
    else         asm volatile("s_waitcnt vmcnt(0)" ::: "memory");
    __builtin_amdgcn_s_barrier();
    if (s + 2 < 24) STAGE2(s + 2);
    const char* L = smem + (s % 3) * 16384;
    __builtin_amdgcn_s_setprio(1);
    mma_step_sw(L, L + 8192, acc, lane, wr, wc);
    __builtin_amdgcn_s_setprio(0);
  }
#undef STAGE2
  (void)srow;
  // epilogue: relu(acc + bs) -> out (written exactly once)
  int colb = e0 + wc * 64 + (lane & 15);
#pragma unroll
  for (int c = 0; c < 4; ++c) {
    int col = colb + c * 16;
    float bv = bs[col];
#pragma unroll
    for (int r = 0; r < 4; ++r)
#pragma unroll
      for (int q = 0; q < 4; ++q) {
        int m = b * NN + rowb + r * 16 + q;
        out[(size_t)m * DD + col] = fmaxf(acc[r][c][q] + bv, 0.f);
      }
  }
}

// ---------------- launch ----------------
extern "C" void kernel_launch(void* const* d_in, const int* in_sizes, int n_in,
                              void* d_out, int out_size, void* d_ws, size_t ws_size,
                              hipStream_t stream) {
  const float* node = (const float*)d_in[0];
  const int* mask   = (const int*)d_in[1];
  const int* arg    = (const int*)d_in[2];
  const int* pun    = (const int*)d_in[3];
  const float* Wq   = (const float*)d_in[4];
  const float* bq   = (const float*)d_in[5];
  const float* Ws   = (const float*)d_in[6];
  const float* bs   = (const float*)d_in[7];
  const float* Wa   = (const float*)d_in[8];
  const float* Wp   = (const float*)d_in[9];
  const float* Wap  = (const float*)d_in[10];
  const float* Wpp  = (const float*)d_in[11];
  const float* Wa2  = (const float*)d_in[12];
  const float* Wp2  = (const float*)d_in[13];
  const float* Wap2 = (const float*)d_in[14];
  const float* Wpp2 = (const float*)d_in[15];

  float* out  = (float*)d_out;              // node: 16384*768 fp32
  float* allw = out + (size_t)MM * DD;      // all_weight: 16384 fp32

  char* ws = (char*)d_ws;
  bf16* node_bf = (bf16*)ws;                    // 25,165,824 B
  float* dw     = (float*)(ws + 25165824);      //     65,536 B
  float* neigh  = (float*)(ws + 25231360);      //     65,536 B
  bf16* Wcat4   = (bf16*)(ws + 25296896);       //  4,718,592 B  bf16 combined rel weights
  bf16* Ws_bf   = (bf16*)(ws + 30015488);       //  1,179,648 B
  u8*   g8      = (u8*)(ws + 31195136);         // 16,777,216 B  fp8 tiled
  u8*   p8      = (u8*)(ws + 47972352);         // 50,331,648 B  fp8 tiled
  (void)ws_size; (void)in_sizes; (void)n_in; (void)out_size;

  k_pre<<<MM / 4 + WSZ / 256, 256, 0, stream>>>(node, Wq, bq, node_bf, dw, allw,
                                                neigh, Ws, Wa, Wp, Wap, Wpp,
                                                Wa2, Wp2, Wap2, Wpp2, Wcat4, Ws_bf);
  k_graph<<<BB * 16, 256, 0, stream>>>(mask, arg, pun, dw, g8, neigh);
  k_proj<<<768, 512, 0, stream>>>(node_bf, Wcat4, p8);
  k_agg<<<12 * BB, 256, 0, stream>>>(g8, p8, node_bf, Ws_bf, neigh, bs, out);
}

// Round 6
// 301.691 us; speedup vs baseline: 1.1123x; 1.0198x over previous
//
#include <hip/hip_runtime.h>
#include <hip/hip_bf16.h>
#include <math.h>

typedef __bf16 bf16;
typedef unsigned char u8;
typedef unsigned long long ull;
typedef __bf16 bf16x8 __attribute__((ext_vector_type(8)));
typedef float f32x4 __attribute__((ext_vector_type(4)));

#define BB 64
#define NN 256
#define DD 768
#define MM (BB*NN)           // 16384
#define KP 1024              // agg phase-1 K (4 relations * 256)
#define WSZ (DD*DD)          // 589824
#define TL2 272              // fp8 transpose buffer row stride (16B-aligned)
#define AROW2 196608         // 128 rows * 1536 B (staging round-1 offset)

// fp8 tiled layout: [tile][koq(4)][m(128)] -> 4096B tiles, koq = (K%32)/8
// g8 tile id: (b*2 + i/128)*32 + K/32          (16 MB total)
// p8 tile id: (b*6 + e/128)*32 + K/32          (50 MB total)

// ---------------- async global->LDS (16B per lane) ----------------
__device__ __forceinline__ void async16(const void* g, void* l) {
  __builtin_amdgcn_global_load_lds((__attribute__((address_space(1))) void*)g,
                                   (__attribute__((address_space(3))) void*)l,
                                   16, 0, 0);
}

// one BK=32 fp8 step on a K-major-8B tiled slab: conflict-free b64 reads
__device__ __forceinline__ void mma_step_fp8t(const char* lA, const char* lB,
                                              f32x4 acc[4][4], int lane, int wr, int wc) {
  long af[4], bfr[4];
  int koq = (lane >> 4) * 1024;
  int mA = (wr * 64 + (lane & 15)) * 8;
  int mB = (wc * 64 + (lane & 15)) * 8;
#pragma unroll
  for (int r = 0; r < 4; ++r)
    af[r] = *(const long*)(lA + koq + mA + r * 128);
#pragma unroll
  for (int c = 0; c < 4; ++c)
    bfr[c] = *(const long*)(lB + koq + mB + c * 128);
#pragma unroll
  for (int r = 0; r < 4; ++r)
#pragma unroll
    for (int c = 0; c < 4; ++c)
      acc[r][c] = __builtin_amdgcn_mfma_f32_16x16x32_fp8_fp8(af[r], bfr[c], acc[r][c], 0, 0, 0);
}

// one BK=32 bf16 step on a swizzled [128][32] slab (row 64B; slot ^= (row>>1)&3)
__device__ __forceinline__ void mma_step_sw(const char* lA, const char* lB,
                                            f32x4 acc[4][4], int lane, int wr, int wc) {
  bf16x8 af[4], bfr[4];
  int rbase = wr * 64 + (lane & 15);
  int cbase = wc * 64 + (lane & 15);
  int sSw = ((lane >> 4) ^ (((lane & 15) >> 1) & 3)) * 16;
#pragma unroll
  for (int r = 0; r < 4; ++r)
    af[r] = *(const bf16x8*)(lA + (rbase + r * 16) * 64 + sSw);
#pragma unroll
  for (int c = 0; c < 4; ++c)
    bfr[c] = *(const bf16x8*)(lB + (cbase + c * 16) * 64 + sSw);
#pragma unroll
  for (int r = 0; r < 4; ++r)
#pragma unroll
    for (int c = 0; c < 4; ++c)
      acc[r][c] = __builtin_amdgcn_mfma_f32_16x16x32_bf16(af[r], bfr[c], acc[r][c], 0, 0, 0);
}

// pack 4 floats -> 4 fp8(e4m3) in a uint
__device__ __forceinline__ unsigned pack4(float a, float b, float c, float d) {
  int w = 0;
  w = __builtin_amdgcn_cvt_pk_fp8_f32(a, b, w, false);
  w = __builtin_amdgcn_cvt_pk_fp8_f32(c, d, w, true);
  return (unsigned)w;
}

// ---------------- K0: fused prep (dw/cast/zero-neigh) + weight combine ----------------
__global__ void k_pre(const float* __restrict__ node, const float* __restrict__ Wq,
                      const float* __restrict__ bq, bf16* __restrict__ node_bf,
                      float* __restrict__ dw, float* __restrict__ allw,
                      float* __restrict__ neigh,
                      const float* __restrict__ Ws,
                      const float* __restrict__ Wa, const float* __restrict__ Wp,
                      const float* __restrict__ Wap, const float* __restrict__ Wpp,
                      const float* __restrict__ Wa2, const float* __restrict__ Wp2,
                      const float* __restrict__ Wap2, const float* __restrict__ Wpp2,
                      bf16* __restrict__ Wcat4, bf16* __restrict__ Ws_bf) {
  if (blockIdx.x < MM / 4) {
    int lane = threadIdx.x & 63, wv = threadIdx.x >> 6;
    int row = blockIdx.x * 4 + wv;
    const float* nr = node + (size_t)row * DD;
    bf16* nb = node_bf + (size_t)row * DD;
    float s = 0.f;
#pragma unroll
    for (int k = 0; k < DD / 64; ++k) {
      int idx = lane + k * 64;
      float v = nr[idx];
      nb[idx] = (bf16)v;
      s += v * Wq[idx];
    }
#pragma unroll
    for (int off = 32; off; off >>= 1) s += __shfl_down(s, off);
    if (lane == 0) {
      float z = s + bq[0];
      float d = 1.f / (1.f + expf(-z));
      dw[row] = d;
      allw[row] = d;
      neigh[row] = 0.f;
    }
  } else {
    int i = (blockIdx.x - MM / 4) * 256 + threadIdx.x;   // 0..589823
    Ws_bf[i] = (bf16)Ws[i];
    Wcat4[i]           = (bf16)(Wa[i] + Wa2[i]);
    Wcat4[i + WSZ]     = (bf16)(Wp[i] + Wp2[i]);
    Wcat4[i + 2 * WSZ] = (bf16)(Wap[i] + Wap2[i]);
    Wcat4[i + 3 * WSZ] = (bf16)(Wpp[i] + Wpp2[i]);
  }
}

// store a 16B (two 8B koq pieces) value into the tiled fp8 layout
__device__ __forceinline__ void store_tiled(u8* base, int tile, int kin, int m, uint4 v) {
  size_t o = (size_t)tile * 4096 + (size_t)((kin >> 3) * 1024 + m * 8);
  *(ull*)(base + o)        = ((ull)v.y << 32) | v.x;
  *(ull*)(base + o + 1024) = ((ull)v.w << 32) | v.z;
}

// ---------------- K0b: g8 tiled = fp8(dw_src * g_X), neigh (atomic) ----------------
__global__ void k_graph(const int* __restrict__ mask, const int* __restrict__ arg,
                        const int* __restrict__ pun, const float* __restrict__ dw,
                        u8* __restrict__ g8, float* __restrict__ neigh) {
  __shared__ float la[64][65];
  __shared__ float lp[64][65];
  __shared__ float msk[256];
  __shared__ float dwv[256];
  int tid = threadIdx.x;
  int bi = blockIdx.x;
  int b = bi >> 4, it = (bi >> 2) & 3, jt = bi & 3;
  int i0 = it * 64, j0 = jt * 64;
  msk[tid] = (float)mask[b * NN + tid];
  dwv[tid] = dw[b * NN + tid];
  __syncthreads();
  int ir = tid >> 2, c4 = (tid & 3) * 16;
  int i = i0 + ir;
  float mi = msk[i];
  size_t gb = (size_t)b * NN * NN;
  const int* ap = arg + gb + (size_t)i * NN + j0 + c4;
  const int* pp = pun + gb + (size_t)i * NN + j0 + c4;
  float va[16], vp[16];
  float racc = 0.f;
#pragma unroll
  for (int k = 0; k < 16; ++k) {
    int j = j0 + c4 + k;
    float dd = (i == j) ? 0.f : mi * msk[j];
    float ga = dd * (float)ap[k];
    float gp = dd * (float)pp[k];
    la[ir][c4 + k] = ga;
    lp[ir][c4 + k] = gp;
    float w = dwv[j];
    va[k] = w * ga;
    vp[k] = w * gp;
    racc += ga + gp;
  }
  uint4 oa, op;
#pragma unroll
  for (int g = 0; g < 4; ++g) {
    (&oa.x)[g] = pack4(va[g*4], va[g*4+1], va[g*4+2], va[g*4+3]);
    (&op.x)[g] = pack4(vp[g*4], vp[g*4+1], vp[g*4+2], vp[g*4+3]);
  }
  {
    int tR = (b * 2 + (i >> 7)) * 32;
    int K0 = j0 + c4;                       // X=0 K index; X=1 adds 256 (+8 tiles)
    store_tiled(g8, tR + (K0 >> 5),       K0 & 31, i & 127, oa);
    store_tiled(g8, tR + 8 + (K0 >> 5),   K0 & 31, i & 127, op);
  }
  racc += __shfl_xor(racc, 1);
  racc += __shfl_xor(racc, 2);
  if ((tid & 3) == 0) atomicAdd(&neigh[b * NN + i], racc);
  __syncthreads();
  int jr = ir, ic4 = c4;
  float cacc = 0.f;
#pragma unroll
  for (int k = 0; k < 16; ++k) {
    float ga = la[ic4 + k][jr];
    float gp = lp[ic4 + k][jr];
    float w = dwv[i0 + ic4 + k];
    va[k] = w * ga;
    vp[k] = w * gp;
    cacc += ga + gp;
  }
#pragma unroll
  for (int g = 0; g < 4; ++g) {
    (&oa.x)[g] = pack4(va[g*4], va[g*4+1], va[g*4+2], va[g*4+3]);
    (&op.x)[g] = pack4(vp[g*4], vp[g*4+1], vp[g*4+2], vp[g*4+3]);
  }
  {
    int row = j0 + jr;
    int tR = (b * 2 + (row >> 7)) * 32;
    int K2 = i0 + ic4;                      // X=2 base 512 (+16 tiles); X=3 +24
    store_tiled(g8, tR + 16 + (K2 >> 5),  K2 & 31, row & 127, oa);
    store_tiled(g8, tR + 24 + (K2 >> 5),  K2 & 31, row & 127, op);
  }
  cacc += __shfl_xor(cacc, 1);
  cacc += __shfl_xor(cacc, 2);
  if ((tid & 3) == 0) atomicAdd(&neigh[b * NN + j0 + jr], cacc);
}

// ---------------- K1: p8 tiled = fp8((node @ WX^T)^T) ----------------
// v6: m201-discipline phase order. Same 256x256 tile, 8 waves, BK=32, 4x32KB
// ring, same swizzle/staging as rounds 2-5; the ONE change: per-phase order is
//   { ds_read(tile T) ; stage(tile T+3) ; sched_bar ; s_barrier ;
//     lgkmcnt(0) ; sched_bar ; setprio(1) ; 32 MFMA ; setprio(0) ;
//     counted vmcnt ; sched_bar ; s_barrier }
// so the 12 frag reads ISSUE before the barrier and drain during barrier skew
// and under other waves' MFMAs (lgkm-wait is post-barrier), instead of
// serializing before (r1) or after (r2/r3) the MFMA cluster.
// WAR: stage slot (T+3)&3 == (T-1)&3; tile T-1 reads drained at phase T-1's
// lgkmcnt(0), which precedes bar2(T-1) < phase T. vmcnt ledger (4 loads/tile,
// stage T+3 at phase T): outstanding at phase-T end = tiles T+1,T+2,T+3 = 12;
// vmcnt(8) => tile T+1 resident for all waves after bar2. Tail 8->4->0.
template<int T>
__device__ __forceinline__ void proj_ph(char* smem, int wvoff,
                                        const char* gA, const char* gB,
                                        int aoff, int boff,
                                        f32x4 (&acc)[8][4]) {
  const char* L = smem + (T & 3) * 32768;
  bf16x8 af[8], bfr[4];
#pragma unroll
  for (int r = 0; r < 8; ++r) af[r] = *(const bf16x8*)(L + aoff + r * 1024);
#pragma unroll
  for (int c = 0; c < 4; ++c) bfr[c] = *(const bf16x8*)(L + boff + c * 1024);
  if constexpr (T + 3 < 24) {                 // stage tile T+3 -> slot (T+3)&3
    char* D = smem + ((T + 3) & 3) * 32768 + wvoff;
    const char* sA = gA + (T + 3) * 64;
    const char* sB = gB + (T + 3) * 64;
    async16(sA,         D);
    async16(sA + AROW2, D + 8192);
    async16(sB,         D + 16384);
    async16(sB + AROW2, D + 24576);
  }
  __builtin_amdgcn_sched_barrier(0);
  __builtin_amdgcn_s_barrier();
  asm volatile("s_waitcnt lgkmcnt(0)" ::: "memory");
  __builtin_amdgcn_sched_barrier(0);
  __builtin_amdgcn_s_setprio(1);
#pragma unroll
  for (int r = 0; r < 8; ++r)
#pragma unroll
    for (int c = 0; c < 4; ++c)
      acc[r][c] = __builtin_amdgcn_mfma_f32_16x16x32_bf16(af[r], bfr[c], acc[r][c], 0, 0, 0);
  __builtin_amdgcn_s_setprio(0);
  if constexpr (T <= 20)      asm volatile("s_waitcnt vmcnt(8)" ::: "memory");
  else if constexpr (T == 21) asm volatile("s_waitcnt vmcnt(4)" ::: "memory");
  else if constexpr (T == 22) asm volatile("s_waitcnt vmcnt(0)" ::: "memory");
  __builtin_amdgcn_sched_barrier(0);
  __builtin_amdgcn_s_barrier();
}

__global__ __launch_bounds__(512, 2) void k_proj(const bf16* __restrict__ node_bf,
                                                 const bf16* __restrict__ Wcat4,
                                                 u8* __restrict__ p8) {
  __shared__ __align__(16) char smem[131072];
  int tid = threadIdx.x, lane = tid & 63, wv = tid >> 6;
  int wr = wv >> 2, wc = wv & 3;
  int l = blockIdx.x, xcd = l & 7, idx = l >> 3;
  int b = (idx / 12) * 8 + xcd;          // 64 b-tiles (M-tile = one full b)
  int nt = idx % 12;                     // 12 N-tiles of 256 over (X,e)
  int n0 = nt * 256;
  int m0 = b * 256;
  int srcS = (tid & 3) ^ ((tid >> 3) & 3);
  const char* gA = (const char*)node_bf + (size_t)m0 * 1536 + (tid >> 2) * 1536 + srcS * 16;
  const char* gB = (const char*)Wcat4  + (size_t)n0 * 1536 + (tid >> 2) * 1536 + srcS * 16;
  int wvoff = wv * 1024;
  int sSwR = ((lane >> 4) ^ (((lane & 15) >> 1) & 3)) << 4;
  int aoff = (wr * 128 + (lane & 15)) * 64 + sSwR;
  int boff = 16384 + (wc * 64 + (lane & 15)) * 64 + sSwR;
  f32x4 z = {0.f, 0.f, 0.f, 0.f};
  f32x4 acc[8][4];
#pragma unroll
  for (int r = 0; r < 8; ++r)
#pragma unroll
    for (int c = 0; c < 4; ++c) acc[r][c] = z;
  // prologue: stage tiles 0,1,2 (12 loads/thread); vmcnt(8) => tile 0 resident
#pragma unroll
  for (int u = 0; u < 3; ++u) {
    char* D = smem + u * 32768 + wvoff;
    const char* sA = gA + u * 64;
    const char* sB = gB + u * 64;
    async16(sA,         D);
    async16(sA + AROW2, D + 8192);
    async16(sB,         D + 16384);
    async16(sB + AROW2, D + 24576);
  }
  asm volatile("s_waitcnt vmcnt(8)" ::: "memory");
  __builtin_amdgcn_s_barrier();
  __builtin_amdgcn_sched_barrier(0);
  proj_ph< 0>(smem, wvoff, gA, gB, aoff, boff, acc);
  proj_ph< 1>(smem, wvoff, gA, gB, aoff, boff, acc);
  proj_ph< 2>(smem, wvoff, gA, gB, aoff, boff, acc);
  proj_ph< 3>(smem, wvoff, gA, gB, aoff, boff, acc);
  proj_ph< 4>(smem, wvoff, gA, gB, aoff, boff, acc);
  proj_ph< 5>(smem, wvoff, gA, gB, aoff, boff, acc);
  proj_ph< 6>(smem, wvoff, gA, gB, aoff, boff, acc);
  proj_ph< 7>(smem, wvoff, gA, gB, aoff, boff, acc);
  proj_ph< 8>(smem, wvoff, gA, gB, aoff, boff, acc);
  proj_ph< 9>(smem, wvoff, gA, gB, aoff, boff, acc);
  proj_ph<10>(smem, wvoff, gA, gB, aoff, boff, acc);
  proj_ph<11>(smem, wvoff, gA, gB, aoff, boff, acc);
  proj_ph<12>(smem, wvoff, gA, gB, aoff, boff, acc);
  proj_ph<13>(smem, wvoff, gA, gB, aoff, boff, acc);
  proj_ph<14>(smem, wvoff, gA, gB, aoff, boff, acc);
  proj_ph<15>(smem, wvoff, gA, gB, aoff, boff, acc);
  proj_ph<16>(smem, wvoff, gA, gB, aoff, boff, acc);
  proj_ph<17>(smem, wvoff, gA, gB, aoff, boff, acc);
  proj_ph<18>(smem, wvoff, gA, gB, aoff, boff, acc);
  proj_ph<19>(smem, wvoff, gA, gB, aoff, boff, acc);
  proj_ph<20>(smem, wvoff, gA, gB, aoff, boff, acc);
  proj_ph<21>(smem, wvoff, gA, gB, aoff, boff, acc);
  proj_ph<22>(smem, wvoff, gA, gB, aoff, boff, acc);
  proj_ph<23>(smem, wvoff, gA, gB, aoff, boff, acc);
  // epilogue: C^T -> fp8 -> tiled p8 (unchanged; k_agg layout-compatible)
  __syncthreads();
  u8* tb = (u8*)smem;                    // [256 n][TL2] fp8
  int X = n0 / DD, e0 = n0 % DD;
#pragma unroll
  for (int r = 0; r < 8; ++r)
#pragma unroll
    for (int c = 0; c < 4; ++c) {
      int n = wc * 64 + c * 16 + (lane & 15);
      int m = wr * 128 + r * 16 + ((lane >> 4) << 2);
      *(unsigned*)(tb + n * TL2 + m) =
          pack4(acc[r][c][0], acc[r][c][1], acc[r][c][2], acc[r][c][3]);
    }
  __syncthreads();
#pragma unroll
  for (int t2 = 0; t2 < 8; ++t2) {
    int erow = t2 * 32 + (tid & 31);     // e offset 0..255
    int col = (tid >> 5) * 16;           // j offset 0..240
    uint4 v = *(const uint4*)(tb + erow * TL2 + col);
    int e = e0 + erow;
    int tR = (b * 6 + (e >> 7)) * 32 + X * 8;
    store_tiled(p8, tR + (col >> 5), col & 31, e & 127, v);
  }
}

// ---------------- K2: out = relu(rdenom*(g8 @ p8) + node @ Ws^T + bs) ----------------
// Round-5 version (verified win): counted-vmcnt depth-2 pipelines, 3x16KB bufs,
// 3 blocks/CU, phase-2 both-sides XOR swizzle.
__global__ __launch_bounds__(256, 3) void k_agg(const u8* __restrict__ g8,
                                                const u8* __restrict__ p8,
                                                const bf16* __restrict__ node_bf,
                                                const bf16* __restrict__ Ws_bf,
                                                const float* __restrict__ neigh,
                                                const float* __restrict__ bs,
                                                float* __restrict__ out) {
  __shared__ __align__(16) char smem[49152];
  int tid = threadIdx.x, lane = tid & 63, wv = tid >> 6, wr = wv >> 1, wc = wv & 1;
  int l = blockIdx.x;
  int xcd = l & 7, idx = l >> 3;
  int b = (idx / 12) * 8 + xcd;
  int t = idx % 12;
  int i0 = (t / 6) * 128, e0 = (t % 6) * 128;
  f32x4 z = {0.f, 0.f, 0.f, 0.f};
  f32x4 acc[4][4];
#pragma unroll
  for (int r = 0; r < 4; ++r)
#pragma unroll
    for (int c = 0; c < 4; ++c) acc[r][c] = z;
  // ---- phase 1: agg_raw = g8 @ p8 (K=1024 fp8 tiled, BK=64/step, 16 steps) ----
  const u8* At = g8 + (size_t)((b * 2 + (i0 >> 7)) * 32) * 4096;
  const u8* Bt = p8 + (size_t)((b * 6 + (e0 >> 7)) * 32) * 4096;
  int gOff = tid * 16;                   // linear 16B slot within a 4KB tile
  int lOff = wv * 1024;                  // wave-uniform LDS dest base
#pragma unroll
  for (int u = 0; u < 2; ++u) {
    char* D = smem + u * 16384 + lOff;
    const u8* a0 = At + (size_t)(2 * u) * 4096 + gOff;
    const u8* b0 = Bt + (size_t)(2 * u) * 4096 + gOff;
    async16(a0, D);            async16(a0 + 4096, D + 4096);
    async16(b0, D + 8192);     async16(b0 + 4096, D + 12288);
  }
  for (int s = 0; s < 16; ++s) {
    if (s <= 14) asm volatile("s_waitcnt vmcnt(4)" ::: "memory");
    else         asm volatile("s_waitcnt vmcnt(0)" ::: "memory");
    __builtin_amdgcn_s_barrier();
    if (s + 2 < 16) {                    // stage step s+2 -> buf (s+2)%3
      char* D = smem + ((s + 2) % 3) * 16384 + lOff;
      const u8* a0 = At + (size_t)(2 * (s + 2)) * 4096 + gOff;
      const u8* b0 = Bt + (size_t)(2 * (s + 2)) * 4096 + gOff;
      async16(a0, D);          async16(a0 + 4096, D + 4096);
      async16(b0, D + 8192);   async16(b0 + 4096, D + 12288);
    }
    const char* L = smem + (s % 3) * 16384;
    __builtin_amdgcn_s_setprio(1);
    mma_step_fp8t(L,        L + 8192,  acc, lane, wr, wc);
    mma_step_fp8t(L + 4096, L + 12288, acc, lane, wr, wc);
    __builtin_amdgcn_s_setprio(0);
  }
  // inter-phase: scale by 1/denom (registers only)
  int rowb = i0 + wr * 64 + (lane >> 4) * 4;
#pragma unroll
  for (int r = 0; r < 4; ++r)
#pragma unroll
    for (int q = 0; q < 4; ++q) {
      float rd = 1.f / fmaxf(neigh[b * NN + rowb + r * 16 + q], 1.f);
#pragma unroll
      for (int c = 0; c < 4; ++c) acc[r][c][q] *= rd;
    }
  __syncthreads();                       // all phase-1 reads done before reuse
  // ---- phase 2: + node @ Ws^T (K=768 bf16, BK=32/step, 24 steps) ----
  const bf16* Ab2 = node_bf + (size_t)(b * NN + i0) * DD;
  const bf16* Bb2 = Ws_bf + (size_t)e0 * DD;
  int scol = ((lane & 3) ^ ((lane >> 3) & 3)) * 8;   // pre-swizzled src col
#define STAGE2(u)                                                              \
  {                                                                            \
    char* D = smem + ((u) % 3) * 16384;                                        \
    _Pragma("unroll")                                                          \
    for (int cc = 0; cc < 2; ++cc) {                                           \
      int c = wv * 2 + cc;                                                     \
      int row = c * 16 + (lane >> 2);                                          \
      async16(Ab2 + (size_t)row * DD + (u) * 32 + scol, D + c * 1024);         \
      async16(Bb2 + (size_t)row * DD + (u) * 32 + scol, D + 8192 + c * 1024);  \
    }                                                                          \
  }
  STAGE2(0);
  STAGE2(1);
  for (int s = 0; s < 24; ++s) {
    if (s <= 22) asm volatile("s_waitcnt vmcnt(4)" ::: "memory");
    else         asm volatile("s_waitcnt vmcnt(0)" ::: "memory");
    __builtin_amdgcn_s_barrier();
    if (s + 2 < 24) STAGE2(s + 2);
    const char* L = smem + (s % 3) * 16384;
    __builtin_amdgcn_s_setprio(1);
    mma_step_sw(L, L + 8192, acc, lane, wr, wc);
    __builtin_amdgcn_s_setprio(0);
  }
#undef STAGE2
  // epilogue: relu(acc + bs) -> out (written exactly once)
  int colb = e0 + wc * 64 + (lane & 15);
#pragma unroll
  for (int c = 0; c < 4; ++c) {
    int col = colb + c * 16;
    float bv = bs[col];
#pragma unroll
    for (int r = 0; r < 4; ++r)
#pragma unroll
      for (int q = 0; q < 4; ++q) {
        int m = b * NN + rowb + r * 16 + q;
        out[(size_t)m * DD + col] = fmaxf(acc[r][c][q] + bv, 0.f);
      }
  }
}

// ---------------- launch ----------------
extern "C" void kernel_launch(void* const* d_in, const int* in_sizes, int n_in,
                              void* d_out, int out_size, void* d_ws, size_t ws_size,
                              hipStream_t stream) {
  const float* node = (const float*)d_in[0];
  const int* mask   = (const int*)d_in[1];
  const int* arg    = (const int*)d_in[2];
  const int* pun    = (const int*)d_in[3];
  const float* Wq   = (const float*)d_in[4];
  const float* bq   = (const float*)d_in[5];
  const float* Ws   = (const float*)d_in[6];
  const float* bs   = (const float*)d_in[7];
  const float* Wa   = (const float*)d_in[8];
  const float* Wp   = (const float*)d_in[9];
  const float* Wap  = (const float*)d_in[10];
  const float* Wpp  = (const float*)d_in[11];
  const float* Wa2  = (const float*)d_in[12];
  const float* Wp2  = (const float*)d_in[13];
  const float* Wap2 = (const float*)d_in[14];
  const float* Wpp2 = (const float*)d_in[15];

  float* out  = (float*)d_out;              // node: 16384*768 fp32
  float* allw = out + (size_t)MM * DD;      // all_weight: 16384 fp32

  char* ws = (char*)d_ws;
  bf16* node_bf = (bf16*)ws;                    // 25,165,824 B
  float* dw     = (float*)(ws + 25165824);      //     65,536 B
  float* neigh  = (float*)(ws + 25231360);      //     65,536 B
  bf16* Wcat4   = (bf16*)(ws + 25296896);       //  4,718,592 B  bf16 combined rel weights
  bf16* Ws_bf   = (bf16*)(ws + 30015488);       //  1,179,648 B
  u8*   g8      = (u8*)(ws + 31195136);         // 16,777,216 B  fp8 tiled
  u8*   p8      = (u8*)(ws + 47972352);         // 50,331,648 B  fp8 tiled
  (void)ws_size; (void)in_sizes; (void)n_in; (void)out_size;

  k_pre<<<MM / 4 + WSZ / 256, 256, 0, stream>>>(node, Wq, bq, node_bf, dw, allw,
                                                neigh, Ws, Wa, Wp, Wap, Wpp,
                                                Wa2, Wp2, Wap2, Wpp2, Wcat4, Ws_bf);
  k_graph<<<BB * 16, 256, 0, stream>>>(mask, arg, pun, dw, g8, neigh);
  k_proj<<<768, 512, 0, stream>>>(node_bf, Wcat4, p8);
  k_agg<<<12 * BB, 256, 0, stream>>>(g8, p8, node_bf, Ws_bf, neigh, bs, out);
}